// Round 5
// baseline (367.756 us; speedup 1.0000x reference)
//
#include <hip/hip_runtime.h>
#include <stdint.h>

typedef unsigned short ushort_t;
typedef __bf16 bf16x8 __attribute__((ext_vector_type(8)));
typedef float floatx4 __attribute__((ext_vector_type(4)));
typedef float floatx16 __attribute__((ext_vector_type(16)));
typedef unsigned short ushort8 __attribute__((ext_vector_type(8)));

__device__ __forceinline__ ushort_t f2b(float f) {
  union { float f; unsigned u; } v; v.f = f;
  unsigned r = v.u + 0x7fffu + ((v.u >> 16) & 1u);  // RNE
  return (ushort_t)(r >> 16);
}
__device__ __forceinline__ ushort_t b2u(float f) {  // native hw cvt
  union { __bf16 b; ushort_t u; } v; v.b = (__bf16)f; return v.u;
}
__device__ __forceinline__ bf16x8 cvt8(const float* p) {
  floatx4 f0 = *(const floatx4*)p;
  floatx4 f1 = *(const floatx4*)(p + 4);
  union { bf16x8 v; __bf16 e[8]; } u;
#pragma unroll
  for (int j = 0; j < 4; ++j) u.e[j] = (__bf16)f0[j];
#pragma unroll
  for (int j = 0; j < 4; ++j) u.e[4 + j] = (__bf16)f1[j];
  return u.v;
}

// pack two f32 -> one dword of two bf16 (lo = a, hi = b), RNE hw cvt
__device__ __forceinline__ unsigned cvtpk(float a, float b) {
  unsigned r;
  asm("v_cvt_pk_bf16_f32 %0, %1, %2" : "=v"(r) : "v"(a), "v"(b));
  return r;
}
// exchange x.lanes[32..63] <-> y.lanes[0..31]
__device__ __forceinline__ void plswap(unsigned& x, unsigned& y) {
  asm("v_permlane32_swap_b32 %0, %1" : "+v"(x), "+v"(y));
}

// async global->LDS, 16 bytes per lane (wave-uniform LDS base + lane*16)
__device__ __forceinline__ void async16(const ushort_t* g, ushort_t* l) {
  __builtin_amdgcn_global_load_lds(
      (const __attribute__((address_space(1))) void*)g,
      (__attribute__((address_space(3))) void*)l, 16, 0, 0);
}

// -------- weight transpose + f32->bf16: src[R][Cc] f32 -> dst[Cc][R] bf16 ----
__global__ void transpose_k(const float* __restrict__ src,
                            ushort_t* __restrict__ dst, int R, int Cc) {
  int idx = blockIdx.x * 256 + threadIdx.x;
  if (idx < R * Cc) {
    int r = idx / Cc, c = idx % Cc;
    dst[(size_t)c * R + r] = f2b(src[idx]);
  }
}

// -------- QKV GEMM with fused f32->bf16 of A --------
// C[M][N] = cvt_bf16(A_f32[M][K]) @ Bt[N][K]^T, C bf16.
// 128x128 tile, 4 waves, BK=64. A: reg-staged (pre-swizzled f32 source ->
// cast -> linear ds_write_b128); B: global_load_lds width-16. Read path
// (XOR chunk^row&7 swizzle) identical to the round-1 verified kernel.
// XCD-aware bijective block swizzle.
__global__ __launch_bounds__(256) void gemm_qkv(
    const float* __restrict__ A,
    const ushort_t* __restrict__ Bt,
    ushort_t* __restrict__ C, int M, int N, int K) {
  __shared__ __align__(16) ushort_t As[128 * 64];
  __shared__ __align__(16) ushort_t Bs[128 * 64];
  const int t = threadIdx.x;
  const int nwg = gridDim.x;
  const int per = nwg >> 3;
  const int swz = (blockIdx.x & 7) * per + (blockIdx.x >> 3);
  const int ntn = N >> 7;
  const int m0 = (swz / ntn) << 7;
  const int n0 = (swz % ntn) << 7;
  const int w = t >> 6, lane = t & 63;
  const int wy = (w >> 1) << 6;
  const int wx = (w & 1) << 6;
  const int l15 = lane & 15;
  const int quad = lane >> 4;
  const int quad4 = quad << 2;
  floatx4 acc[4][4] = {};
  const int srow = t >> 3;
  const int sc = (((t & 7) ^ (srow & 7)) << 3);
  const float* gA = A + (size_t)(m0 + srow) * K + sc;
  const ushort_t* gB = Bt + (size_t)(n0 + srow) * K + sc;
  for (int k0 = 0; k0 < K; k0 += 64) {
    __syncthreads();
#pragma unroll
    for (int r4 = 0; r4 < 4; ++r4) {
      async16(gB + (size_t)r4 * 32 * K + k0, &Bs[r4 * 2048 + t * 8]);
      bf16x8 av = cvt8(gA + (size_t)r4 * 32 * K + k0);
      *(bf16x8*)&As[r4 * 2048 + t * 8] = av;
    }
    __syncthreads();
#pragma unroll
    for (int kk = 0; kk < 2; ++kk) {
      bf16x8 af[4], bfr[4];
#pragma unroll
      for (int i = 0; i < 4; ++i) {
        int row = wy + i * 16 + l15;
        af[i] = *(const bf16x8*)&As[row * 64 + ((((kk << 2) | quad) ^ (row & 7)) << 3)];
      }
#pragma unroll
      for (int j = 0; j < 4; ++j) {
        int row = wx + j * 16 + l15;
        bfr[j] = *(const bf16x8*)&Bs[row * 64 + ((((kk << 2) | quad) ^ (row & 7)) << 3)];
      }
#pragma unroll
      for (int i = 0; i < 4; ++i)
#pragma unroll
        for (int j = 0; j < 4; ++j)
          acc[i][j] = __builtin_amdgcn_mfma_f32_16x16x32_bf16(
              af[i], bfr[j], acc[i][j], 0, 0, 0);
    }
  }
#pragma unroll
  for (int i = 0; i < 4; ++i) {
#pragma unroll
    for (int r = 0; r < 4; ++r) {
      size_t row = (size_t)(m0 + wy + i * 16 + quad4 + r);
      ushort_t* cp = C + row * N + (n0 + wx + l15);
#pragma unroll
      for (int j = 0; j < 4; ++j) cp[j * 16] = f2b(acc[i][j][r]);
    }
  }
}

// -------- fused window attention + proj GEMM (v2: no V staging) --------
// QKV: [B*4096][1152] bf16, col = c3*384 + h*32 + d (read-only here).
// Phase 1: 32x32 MFMA, swapped QK^T, in-register P via cvt_pk +
// permlane32_swap (round-3/4 verified math). V is read DIRECT from global as
// PV B-frags (vf[j] = V[k][d=l31]: lanes 0..31 cover 64 contiguous bytes per
// j -> coalesced; each block's V rows are touched by that block only, so LDS
// staging was pure overhead). Attn-out written bf16 into swizzled LDS Ao.
// Phase 2: per-wave 64x96 stripe of out = Ao @ Bt^T + bias.
// LDS = Ao only (48 KB) -> 3 blocks/CU (was 2 at 67.6 KB).
__global__ __launch_bounds__(256, 3) void attn_proj(
    const ushort_t* __restrict__ QKV, const ushort_t* __restrict__ Bt,
    const float* __restrict__ bias, float* __restrict__ out) {
  __shared__ __align__(16) ushort_t Ao[64 * 384];    // swizzled attn out
  const int blk = blockIdx.x;
  const int b = blk >> 6, g = blk & 63;
  const int gy = g >> 3, gx = g & 7;
  const int t = threadIdx.x, w = t >> 6, lane = t & 63;
  const int l31 = lane & 31, bh = lane >> 5;
  const int l15 = lane & 15, quad = lane >> 4, quad4 = quad << 2;
  // token tok (0..63, iy-major) -> global row = bbase + (tok>>3)*64 + (tok&7)
  const size_t bbase = (size_t)b * 4096 + (size_t)(gy * 8) * 64 + gx * 8;
  const float scale = 0.17677669529663687f;  // 1/sqrt(32)

  // ---------------- phase 1: window attention (3 heads per wave) ----------
  for (int hi = 0; hi < 3; ++hi) {
    const int h = w * 3 + hi;
    const size_t hq = (size_t)h * 32;

    // Q B-frags: Q[q = qt*32+l31][d = dc*16 + bh*8 .. +7]
    bf16x8 qf[2][2];
#pragma unroll
    for (int qt = 0; qt < 2; ++qt) {
      int tok = qt * 32 + l31;
      size_t row = bbase + (size_t)(tok >> 3) * 64 + (tok & 7);
#pragma unroll
      for (int dc = 0; dc < 2; ++dc)
        qf[qt][dc] = *(const bf16x8*)(QKV + row * 1152 + hq + dc * 16 + bh * 8);
    }
    // K A-frags
    bf16x8 kf[2][2];
#pragma unroll
    for (int kt = 0; kt < 2; ++kt) {
      int tok = kt * 32 + l31;
      size_t row = bbase + (size_t)(tok >> 3) * 64 + (tok & 7);
#pragma unroll
      for (int dc = 0; dc < 2; ++dc)
        kf[kt][dc] = *(const bf16x8*)(QKV + row * 1152 + 384 + hq + dc * 16 + bh * 8);
    }
    // V B-frags direct from global, hoisted so loads hide under S + softmax:
    // vf[s][j] = V[k = s*16 + bh*8 + j][d = l31]; k>>3 = 2s+bh, k&7 = j
    bf16x8 vf[4];
#pragma unroll
    for (int s = 0; s < 4; ++s) {
      const ushort_t* vbase =
          QKV + (bbase + (size_t)(2 * s + bh) * 64) * 1152 + 768 + hq + l31;
      union { ushort_t e[8]; bf16x8 v; } vu;
#pragma unroll
      for (int j = 0; j < 8; ++j) vu.e[j] = vbase[(size_t)j * 1152];
      vf[s] = vu.v;
    }

    // S^T = K Q^T: st[kt][qt] lane holds
    // S[q = qt*32+l31][k = kt*32 + (reg&3)+8*(reg>>2)+4*bh]
    floatx16 st[2][2] = {};
#pragma unroll
    for (int kt = 0; kt < 2; ++kt)
#pragma unroll
      for (int qt = 0; qt < 2; ++qt)
#pragma unroll
        for (int dc = 0; dc < 2; ++dc)
          st[kt][qt] = __builtin_amdgcn_mfma_f32_32x32x16_bf16(
              kf[kt][dc], qf[qt][dc], st[kt][qt], 0, 0, 0);

    // softmax: p = exp(s*scale); lane-local partial rowsum + 1 cross-half xchg
    float rs[2] = {0.f, 0.f};
#pragma unroll
    for (int kt = 0; kt < 2; ++kt)
#pragma unroll
      for (int qt = 0; qt < 2; ++qt)
#pragma unroll
        for (int r = 0; r < 16; ++r) {
          float e = __expf(st[kt][qt][r] * scale);
          st[kt][qt][r] = e;
          rs[qt] += e;
        }
#pragma unroll
    for (int qt = 0; qt < 2; ++qt) rs[qt] += __shfl_xor(rs[qt], 32);
    float inv[2] = {1.0f / rs[0], 1.0f / rs[1]};

    // PV: normalized-P A-frags in-register (cvt_pk + permlane swaps)
    floatx16 o[2] = {};
#pragma unroll
    for (int s = 0; s < 4; ++s) {
      const int kt = s >> 1, r1x = (s & 1) << 1;
#pragma unroll
      for (int qt = 0; qt < 2; ++qt) {
        float iv = inv[qt];
        unsigned x0 = cvtpk(st[kt][qt][4 * r1x + 0] * iv, st[kt][qt][4 * r1x + 1] * iv);
        unsigned x1 = cvtpk(st[kt][qt][4 * r1x + 2] * iv, st[kt][qt][4 * r1x + 3] * iv);
        unsigned y0 = cvtpk(st[kt][qt][4 * r1x + 4] * iv, st[kt][qt][4 * r1x + 5] * iv);
        unsigned y1 = cvtpk(st[kt][qt][4 * r1x + 6] * iv, st[kt][qt][4 * r1x + 7] * iv);
        plswap(x0, y0);
        plswap(x1, y1);
        union { unsigned d[4]; bf16x8 v; } pa;
        pa.d[0] = x0; pa.d[1] = x1; pa.d[2] = y0; pa.d[3] = y1;
        o[qt] = __builtin_amdgcn_mfma_f32_32x32x16_bf16(pa.v, vf[s], o[qt], 0, 0, 0);
      }
    }

    // write attn-out to swizzled LDS Ao:
    // elem (tok, k=h*32+l31) at tok*384 + (k&~63) + (((k>>3&7)^(tok&7))<<3) + (k&7)
    const int base64 = (h >> 1) << 6;
    const int cbase = ((h & 1) << 2) | (l31 >> 3);
    const int e7 = l31 & 7;
#pragma unroll
    for (int qt = 0; qt < 2; ++qt)
#pragma unroll
      for (int r = 0; r < 16; ++r) {
        int tok = qt * 32 + (r & 3) + 8 * (r >> 2) + 4 * bh;
        int c = cbase ^ (tok & 7);
        Ao[tok * 384 + base64 + (c << 3) + e7] = b2u(o[qt][r]);
      }
  }

  __syncthreads();  // Ao complete (all waves, all heads)

  // ---------------- phase 2: proj GEMM out = Ao @ Bt^T + bias -------------
  // wave w: rows 0..63, cols [w*96, w*96+96). K = 384, 12 k-steps of 32.
  floatx4 acc[4][6] = {};
  for (int ks = 0; ks < 12; ++ks) {
    bf16x8 af[4];
#pragma unroll
    for (int i = 0; i < 4; ++i) {
      int row = i * 16 + l15;
      int c = (((ks & 1) << 2) | quad) ^ (row & 7);
      af[i] = *(const bf16x8*)&Ao[row * 384 + ((ks >> 1) << 6) + (c << 3)];
    }
    bf16x8 bfr[6];
#pragma unroll
    for (int j = 0; j < 6; ++j) {
      int n = w * 96 + j * 16 + l15;
      bfr[j] = *(const bf16x8*)&Bt[(size_t)n * 384 + ks * 32 + (quad << 3)];
    }
#pragma unroll
    for (int i = 0; i < 4; ++i)
#pragma unroll
      for (int j = 0; j < 6; ++j)
        acc[i][j] = __builtin_amdgcn_mfma_f32_16x16x32_bf16(
            af[i], bfr[j], acc[i][j], 0, 0, 0);
  }

  float bv[6];
#pragma unroll
  for (int j = 0; j < 6; ++j) bv[j] = bias[w * 96 + j * 16 + l15];
#pragma unroll
  for (int i = 0; i < 4; ++i) {
#pragma unroll
    for (int r = 0; r < 4; ++r) {
      int tok = i * 16 + quad4 + r;
      size_t grow = bbase + (size_t)(tok >> 3) * 64 + (tok & 7);
      float* cp = out + grow * 384 + w * 96 + l15;
#pragma unroll
      for (int j = 0; j < 6; ++j) cp[j * 16] = acc[i][j][r] + bv[j];
    }
  }
}

extern "C" void kernel_launch(void* const* d_in, const int* in_sizes, int n_in,
                              void* d_out, int out_size, void* d_ws, size_t ws_size,
                              hipStream_t stream) {
  const float* x      = (const float*)d_in[0];  // [65536][384] f32
  const float* qkv_w  = (const float*)d_in[1];  // [384][1152] f32
  const float* proj_w = (const float*)d_in[2];  // [384][384] f32
  const float* proj_b = (const float*)d_in[3];  // [384] f32
  float* out = (float*)d_out;                   // [65536][384] f32

  const int M = 16 * 4096;  // 65536 tokens
  const size_t need =
      ((size_t)M * 1152 + 1152 * 384 + 384 * 384) * 2;
  if (ws_size < need) return;  // diagnostic: finite absmax => ws too small

  ushort_t* qkv    = (ushort_t*)d_ws;                 // M*1152 bf16
  ushort_t* qkvwT  = qkv + (size_t)M * 1152;          // 1152*384 bf16
  ushort_t* projwT = qkvwT + (size_t)1152 * 384;      // 384*384 bf16

  transpose_k<<<(384 * 1152 + 255) / 256, 256, 0, stream>>>(qkv_w, qkvwT, 384, 1152);
  transpose_k<<<(384 * 384 + 255) / 256, 256, 0, stream>>>(proj_w, projwT, 384, 384);

  // QKV projection with fused x f32->bf16. grid = (M/128)*(1152/128), %8==0
  gemm_qkv<<<(M / 128) * (1152 / 128), 256, 0, stream>>>(
      x, qkvwT, qkv, M, 1152, 384);

  // fused window attention + proj
  attn_proj<<<16 * 64, 256, 0, stream>>>(qkv, projwT, proj_b, out);
}

// Round 7
// 357.544 us; speedup vs baseline: 1.0286x; 1.0286x over previous
//
#include <hip/hip_runtime.h>
#include <stdint.h>

typedef unsigned short ushort_t;
typedef __bf16 bf16x8 __attribute__((ext_vector_type(8)));
typedef float floatx4 __attribute__((ext_vector_type(4)));
typedef float floatx16 __attribute__((ext_vector_type(16)));
typedef unsigned short ushort8 __attribute__((ext_vector_type(8)));

__device__ __forceinline__ ushort_t f2b(float f) {
  union { float f; unsigned u; } v; v.f = f;
  unsigned r = v.u + 0x7fffu + ((v.u >> 16) & 1u);  // RNE
  return (ushort_t)(r >> 16);
}
__device__ __forceinline__ ushort_t b2u(float f) {  // native hw cvt
  union { __bf16 b; ushort_t u; } v; v.b = (__bf16)f; return v.u;
}
__device__ __forceinline__ bf16x8 cvt8(const float* p) {
  floatx4 f0 = *(const floatx4*)p;
  floatx4 f1 = *(const floatx4*)(p + 4);
  union { bf16x8 v; __bf16 e[8]; } u;
#pragma unroll
  for (int j = 0; j < 4; ++j) u.e[j] = (__bf16)f0[j];
#pragma unroll
  for (int j = 0; j < 4; ++j) u.e[4 + j] = (__bf16)f1[j];
  return u.v;
}

// pack two f32 -> one dword of two bf16 (lo = a, hi = b), RNE hw cvt
__device__ __forceinline__ unsigned cvtpk(float a, float b) {
  unsigned r;
  asm("v_cvt_pk_bf16_f32 %0, %1, %2" : "=v"(r) : "v"(a), "v"(b));
  return r;
}
// exchange x.lanes[32..63] <-> y.lanes[0..31]
__device__ __forceinline__ void plswap(unsigned& x, unsigned& y) {
  asm("v_permlane32_swap_b32 %0, %1" : "+v"(x), "+v"(y));
}

// async global->LDS, 16 bytes per lane (wave-uniform LDS base + lane*16)
__device__ __forceinline__ void async16(const ushort_t* g, ushort_t* l) {
  __builtin_amdgcn_global_load_lds(
      (const __attribute__((address_space(1))) void*)g,
      (__attribute__((address_space(3))) void*)l, 16, 0, 0);
}

// -------- x f32 -> bf16, 8 elems/thread --------
__global__ __launch_bounds__(256) void cvt_x(const float* __restrict__ src,
                                             ushort_t* __restrict__ dst, int n8) {
  int i = blockIdx.x * 256 + threadIdx.x;
  if (i < n8) *(bf16x8*)&dst[(size_t)i * 8] = cvt8(src + (size_t)i * 8);
}

// -------- weight transpose + f32->bf16: src[R][Cc] f32 -> dst[Cc][R] bf16 ----
__global__ void transpose_k(const float* __restrict__ src,
                            ushort_t* __restrict__ dst, int R, int Cc) {
  int idx = blockIdx.x * 256 + threadIdx.x;
  if (idx < R * Cc) {
    int r = idx / Cc, c = idx % Cc;
    dst[(size_t)c * R + r] = f2b(src[idx]);
  }
}

// -------- QKV GEMM: C[M][N] = A[M][K] @ Bt[N][K]^T, all bf16 ----------------
// 128x128 tile, 4 waves, BK=64, async16 staging for A and B (round-1
// verified), XOR chunk^(row&7) LDS swizzle (both-sides), XCD block swizzle.
// v3 epilogue: MFMA operands SWAPPED (mfma(bfr, af) -> D = C^T fragments) so
// each lane's floatx4 holds 4 consecutive N-cols at one M-row: pack to 4 bf16
// and store 8B per fragment -> 16 stores/lane instead of 64 2B stores.
__global__ __launch_bounds__(256) void gemm_bt(
    const ushort_t* __restrict__ A,
    const ushort_t* __restrict__ Bt,
    ushort_t* __restrict__ C, int M, int N, int K) {
  __shared__ __align__(16) ushort_t As[128 * 64];
  __shared__ __align__(16) ushort_t Bs[128 * 64];
  const int t = threadIdx.x;
  const int nwg = gridDim.x;
  const int per = nwg >> 3;
  const int swz = (blockIdx.x & 7) * per + (blockIdx.x >> 3);
  const int ntn = N >> 7;
  const int m0 = (swz / ntn) << 7;
  const int n0 = (swz % ntn) << 7;
  const int w = t >> 6, lane = t & 63;
  const int wy = (w >> 1) << 6;
  const int wx = (w & 1) << 6;
  const int l15 = lane & 15;
  const int quad = lane >> 4;
  const int quad4 = quad << 2;
  floatx4 acc[4][4] = {};  // acc[jj][ii] = C^T fragment (n-tile jj, m-tile ii)
  const int srow = t >> 3;
  const int sc = (((t & 7) ^ (srow & 7)) << 3);
  const ushort_t* gA = A + (size_t)(m0 + srow) * K + sc;
  const ushort_t* gB = Bt + (size_t)(n0 + srow) * K + sc;
  for (int k0 = 0; k0 < K; k0 += 64) {
    __syncthreads();
#pragma unroll
    for (int r4 = 0; r4 < 4; ++r4) {
      async16(gA + (size_t)r4 * 32 * K + k0, &As[r4 * 2048 + t * 8]);
      async16(gB + (size_t)r4 * 32 * K + k0, &Bs[r4 * 2048 + t * 8]);
    }
    __syncthreads();
#pragma unroll
    for (int kk = 0; kk < 2; ++kk) {
      bf16x8 af[4], bfr[4];
#pragma unroll
      for (int i = 0; i < 4; ++i) {
        int row = wy + i * 16 + l15;
        af[i] = *(const bf16x8*)&As[row * 64 + ((((kk << 2) | quad) ^ (row & 7)) << 3)];
      }
#pragma unroll
      for (int j = 0; j < 4; ++j) {
        int row = wx + j * 16 + l15;
        bfr[j] = *(const bf16x8*)&Bs[row * 64 + ((((kk << 2) | quad) ^ (row & 7)) << 3)];
      }
#pragma unroll
      for (int jj = 0; jj < 4; ++jj)
#pragma unroll
        for (int ii = 0; ii < 4; ++ii)
          acc[jj][ii] = __builtin_amdgcn_mfma_f32_16x16x32_bf16(
              bfr[jj], af[ii], acc[jj][ii], 0, 0, 0);
    }
  }
  // C^T frag: D[row = n-dim: 16jj+quad4+r][col = m-dim: 16ii+l15]
  // -> per lane 4 consecutive n at fixed m: one 8B store.
#pragma unroll
  for (int ii = 0; ii < 4; ++ii) {
    size_t row = (size_t)(m0 + wy + ii * 16 + l15);
#pragma unroll
    for (int jj = 0; jj < 4; ++jj) {
      union { __bf16 e[4]; uint64_t v; } u;
#pragma unroll
      for (int r = 0; r < 4; ++r) u.e[r] = (__bf16)acc[jj][ii][r];
      *(uint64_t*)&C[row * N + (n0 + wx + jj * 16 + quad4)] = u.v;
    }
  }
}

// -------- fused window attention + proj GEMM (v2: no V staging) --------
// QKV: [B*4096][1152] bf16, col = c3*384 + h*32 + d (read-only here).
// Phase 1: 32x32 MFMA, swapped QK^T, in-register P via cvt_pk +
// permlane32_swap (round-3/4 verified math). V read DIRECT from global as
// PV B-frags (coalesced 2B loads; V rows touched by this block only, so LDS
// staging was pure overhead). Attn-out written bf16 into swizzled LDS Ao.
// Phase 2: per-wave 64x96 stripe of out = Ao @ Bt^T + bias.
// LDS = Ao only (48 KB) -> 3 blocks/CU (was 2 at 67.6 KB).
__global__ __launch_bounds__(256, 3) void attn_proj(
    const ushort_t* __restrict__ QKV, const ushort_t* __restrict__ Bt,
    const float* __restrict__ bias, float* __restrict__ out) {
  __shared__ __align__(16) ushort_t Ao[64 * 384];    // swizzled attn out
  const int blk = blockIdx.x;
  const int b = blk >> 6, g = blk & 63;
  const int gy = g >> 3, gx = g & 7;
  const int t = threadIdx.x, w = t >> 6, lane = t & 63;
  const int l31 = lane & 31, bh = lane >> 5;
  const int l15 = lane & 15, quad = lane >> 4, quad4 = quad << 2;
  // token tok (0..63, iy-major) -> global row = bbase + (tok>>3)*64 + (tok&7)
  const size_t bbase = (size_t)b * 4096 + (size_t)(gy * 8) * 64 + gx * 8;
  const float scale = 0.17677669529663687f;  // 1/sqrt(32)

  // ---------------- phase 1: window attention (3 heads per wave) ----------
  for (int hi = 0; hi < 3; ++hi) {
    const int h = w * 3 + hi;
    const size_t hq = (size_t)h * 32;

    // Q B-frags: Q[q = qt*32+l31][d = dc*16 + bh*8 .. +7]
    bf16x8 qf[2][2];
#pragma unroll
    for (int qt = 0; qt < 2; ++qt) {
      int tok = qt * 32 + l31;
      size_t row = bbase + (size_t)(tok >> 3) * 64 + (tok & 7);
#pragma unroll
      for (int dc = 0; dc < 2; ++dc)
        qf[qt][dc] = *(const bf16x8*)(QKV + row * 1152 + hq + dc * 16 + bh * 8);
    }
    // K A-frags
    bf16x8 kf[2][2];
#pragma unroll
    for (int kt = 0; kt < 2; ++kt) {
      int tok = kt * 32 + l31;
      size_t row = bbase + (size_t)(tok >> 3) * 64 + (tok & 7);
#pragma unroll
      for (int dc = 0; dc < 2; ++dc)
        kf[kt][dc] = *(const bf16x8*)(QKV + row * 1152 + 384 + hq + dc * 16 + bh * 8);
    }
    // V B-frags direct from global, hoisted so loads hide under S + softmax:
    // vf[s][j] = V[k = s*16 + bh*8 + j][d = l31]; k>>3 = 2s+bh, k&7 = j
    bf16x8 vf[4];
#pragma unroll
    for (int s = 0; s < 4; ++s) {
      const ushort_t* vbase =
          QKV + (bbase + (size_t)(2 * s + bh) * 64) * 1152 + 768 + hq + l31;
      union { ushort_t e[8]; bf16x8 v; } vu;
#pragma unroll
      for (int j = 0; j < 8; ++j) vu.e[j] = vbase[(size_t)j * 1152];
      vf[s] = vu.v;
    }

    // S^T = K Q^T: st[kt][qt] lane holds
    // S[q = qt*32+l31][k = kt*32 + (reg&3)+8*(reg>>2)+4*bh]
    floatx16 st[2][2] = {};
#pragma unroll
    for (int kt = 0; kt < 2; ++kt)
#pragma unroll
      for (int qt = 0; qt < 2; ++qt)
#pragma unroll
        for (int dc = 0; dc < 2; ++dc)
          st[kt][qt] = __builtin_amdgcn_mfma_f32_32x32x16_bf16(
              kf[kt][dc], qf[qt][dc], st[kt][qt], 0, 0, 0);

    // softmax: p = exp(s*scale); lane-local partial rowsum + 1 cross-half xchg
    float rs[2] = {0.f, 0.f};
#pragma unroll
    for (int kt = 0; kt < 2; ++kt)
#pragma unroll
      for (int qt = 0; qt < 2; ++qt)
#pragma unroll
        for (int r = 0; r < 16; ++r) {
          float e = __expf(st[kt][qt][r] * scale);
          st[kt][qt][r] = e;
          rs[qt] += e;
        }
#pragma unroll
    for (int qt = 0; qt < 2; ++qt) rs[qt] += __shfl_xor(rs[qt], 32);
    float inv[2] = {1.0f / rs[0], 1.0f / rs[1]};

    // PV: normalized-P A-frags in-register (cvt_pk + permlane swaps)
    floatx16 o[2] = {};
#pragma unroll
    for (int s = 0; s < 4; ++s) {
      const int kt = s >> 1, r1x = (s & 1) << 1;
#pragma unroll
      for (int qt = 0; qt < 2; ++qt) {
        float iv = inv[qt];
        unsigned x0 = cvtpk(st[kt][qt][4 * r1x + 0] * iv, st[kt][qt][4 * r1x + 1] * iv);
        unsigned x1 = cvtpk(st[kt][qt][4 * r1x + 2] * iv, st[kt][qt][4 * r1x + 3] * iv);
        unsigned y0 = cvtpk(st[kt][qt][4 * r1x + 4] * iv, st[kt][qt][4 * r1x + 5] * iv);
        unsigned y1 = cvtpk(st[kt][qt][4 * r1x + 6] * iv, st[kt][qt][4 * r1x + 7] * iv);
        plswap(x0, y0);
        plswap(x1, y1);
        union { unsigned d[4]; bf16x8 v; } pa;
        pa.d[0] = x0; pa.d[1] = x1; pa.d[2] = y0; pa.d[3] = y1;
        o[qt] = __builtin_amdgcn_mfma_f32_32x32x16_bf16(pa.v, vf[s], o[qt], 0, 0, 0);
      }
    }

    // write attn-out to swizzled LDS Ao:
    // elem (tok, k=h*32+l31) at tok*384 + (k&~63) + (((k>>3&7)^(tok&7))<<3) + (k&7)
    const int base64 = (h >> 1) << 6;
    const int cbase = ((h & 1) << 2) | (l31 >> 3);
    const int e7 = l31 & 7;
#pragma unroll
    for (int qt = 0; qt < 2; ++qt)
#pragma unroll
      for (int r = 0; r < 16; ++r) {
        int tok = qt * 32 + (r & 3) + 8 * (r >> 2) + 4 * bh;
        int c = cbase ^ (tok & 7);
        Ao[tok * 384 + base64 + (c << 3) + e7] = b2u(o[qt][r]);
      }
  }

  __syncthreads();  // Ao complete (all waves, all heads)

  // ---------------- phase 2: proj GEMM out = Ao @ Bt^T + bias -------------
  // wave w: rows 0..63, cols [w*96, w*96+96). K = 384, 12 k-steps of 32.
  floatx4 acc[4][6] = {};
  for (int ks = 0; ks < 12; ++ks) {
    bf16x8 af[4];
#pragma unroll
    for (int i = 0; i < 4; ++i) {
      int row = i * 16 + l15;
      int c = (((ks & 1) << 2) | quad) ^ (row & 7);
      af[i] = *(const bf16x8*)&Ao[row * 384 + ((ks >> 1) << 6) + (c << 3)];
    }
    bf16x8 bfr[6];
#pragma unroll
    for (int j = 0; j < 6; ++j) {
      int n = w * 96 + j * 16 + l15;
      bfr[j] = *(const bf16x8*)&Bt[(size_t)n * 384 + ks * 32 + (quad << 3)];
    }
#pragma unroll
    for (int i = 0; i < 4; ++i)
#pragma unroll
      for (int j = 0; j < 6; ++j)
        acc[i][j] = __builtin_amdgcn_mfma_f32_16x16x32_bf16(
            af[i], bfr[j], acc[i][j], 0, 0, 0);
  }

  float bv[6];
#pragma unroll
  for (int j = 0; j < 6; ++j) bv[j] = bias[w * 96 + j * 16 + l15];
#pragma unroll
  for (int i = 0; i < 4; ++i) {
#pragma unroll
    for (int r = 0; r < 4; ++r) {
      int tok = i * 16 + quad4 + r;
      size_t grow = bbase + (size_t)(tok >> 3) * 64 + (tok & 7);
      float* cp = out + grow * 384 + w * 96 + l15;
#pragma unroll
      for (int j = 0; j < 6; ++j) cp[j * 16] = acc[i][j][r] + bv[j];
    }
  }
}

extern "C" void kernel_launch(void* const* d_in, const int* in_sizes, int n_in,
                              void* d_out, int out_size, void* d_ws, size_t ws_size,
                              hipStream_t stream) {
  const float* x      = (const float*)d_in[0];  // [65536][384] f32
  const float* qkv_w  = (const float*)d_in[1];  // [384][1152] f32
  const float* proj_w = (const float*)d_in[2];  // [384][384] f32
  const float* proj_b = (const float*)d_in[3];  // [384] f32
  float* out = (float*)d_out;                   // [65536][384] f32

  const int M = 16 * 4096;  // 65536 tokens
  const size_t need =
      ((size_t)M * 1152 + (size_t)M * 384 + 1152 * 384 + 384 * 384) * 2;
  if (ws_size < need) return;  // diagnostic: finite absmax => ws too small

  ushort_t* qkv    = (ushort_t*)d_ws;                 // M*1152 bf16
  ushort_t* xb     = qkv + (size_t)M * 1152;          // M*384 bf16
  ushort_t* qkvwT  = xb + (size_t)M * 384;            // 1152*384 bf16
  ushort_t* projwT = qkvwT + (size_t)1152 * 384;      // 384*384 bf16

  cvt_x<<<(M * 384 / 8 + 255) / 256, 256, 0, stream>>>(x, xb, M * 384 / 8);
  transpose_k<<<(384 * 1152 + 255) / 256, 256, 0, stream>>>(qkv_w, qkvwT, 384, 1152);
  transpose_k<<<(384 * 384 + 255) / 256, 256, 0, stream>>>(proj_w, projwT, 384, 384);

  // QKV projection: grid = (M/128)*(1152/128), %8==0
  gemm_bt<<<(M / 128) * (1152 / 128), 256, 0, stream>>>(
      xb, qkvwT, qkv, M, 1152, 384);

  // fused window attention + proj
  attn_proj<<<16 * 64, 256, 0, stream>>>(qkv, projwT, proj_b, out);
}